// Round 1
// baseline (171.708 us; speedup 1.0000x reference)
//
#include <hip/hip_runtime.h>
#include <hip/hip_bf16.h>

typedef __attribute__((ext_vector_type(4))) float f32x4;
typedef __attribute__((ext_vector_type(8))) short bf16x8;
typedef __attribute__((ext_vector_type(4))) short short4v;
typedef __attribute__((ext_vector_type(8))) short short8v;

#define LDS_STRIDE 40   // 32 k-shorts + 8 pad -> 80 B rows (16B-aligned, min-BW bank spread)
#define C_STRIDE   260  // fp32 epilogue stride: 4-row quad offset = 1040 dwords = 16 mod 32 -> 2-way (free)

__device__ __forceinline__ short f2bf(float f) {
  __hip_bfloat16 h = __float2bfloat16(f);
  return __builtin_bit_cast(short, h);
}

// GEMM view: C[8192 x 512] = A[8192 x 1024] * B[1024 x 512]
//   k = j*4 + kc, kc -> x component {0,1,2,4}
//   n <  256 (c0, i=n)    : B[j*4 + {0,1,2,3}][i]     = {W0,  W1, W2, 0 }
//   n >= 256 (c4, i=n-256): B[j*4 + {0,1,2,3}][256+i] = {0,   W2, -W1, W0}
// One block = 32 rows x all 512 cols (x read exactly once from HBM).
// B-tile rebuilt from fp32 W (L2-resident) each K-step; BK=32 (one MFMA k-step).
__global__ __launch_bounds__(512, 1) void ga_mv_kernel(
    const float* __restrict__ x, const float* __restrict__ W,
    const float* __restrict__ bias, float* __restrict__ y) {
  __shared__ __align__(16) short A_lds[32 * LDS_STRIDE];
  __shared__ __align__(16) short B_lds[512 * LDS_STRIDE];   // 40960 B
  float* c_lds = (float*)&B_lds[0];  // epilogue alias: 32*260*4 = 33280 B <= 40960 B

  const int t    = threadIdx.x;
  const int bm   = blockIdx.x;       // 256 blocks x 32 rows = 8192
  const int lane = t & 63;
  const int w    = t >> 6;           // 8 waves
  const int ln   = lane & 15;
  const int quad = lane >> 4;

  // B staging: thread -> (i = t&255, jp in {2q,2q+1}), q = t>>8
  const int bi = t & 255;
  const int bq = t >> 8;
  // A staging: threads 0..255 -> (row = t>>3, j = t&7); 8 j * 32B = fully-consumed 256B runs
  const int arow = (t >> 3) & 31;
  const int aj   = t & 7;

  const float4* W4 = (const float4*)W;
  const float* xrowp = x + (size_t)(bm * 32 + arow) * 2048;

  float4 wreg[4];
  float4 xreg;
  float  xs = 0.f;

  // prefetch K-tile 0 into registers
  {
#pragma unroll
    for (int c = 0; c < 2; ++c) {
      const int j0 = (bq * 2 + c) * 2;
      wreg[2 * c]     = W4[((j0    ) * 256 + bi) * 2];
      wreg[2 * c + 1] = W4[((j0 + 1) * 256 + bi) * 2];
    }
    if (t < 256) {
      const float* xp = xrowp + aj * 8;
      xreg = *(const float4*)xp;
      xs   = xp[4];
    }
  }

  f32x4 acc[2][4] = {};

  for (int it = 0; it < 32; ++it) {
    // ---- stage prefetched registers -> LDS (bf16 convert fused) ----
#pragma unroll
    for (int c = 0; c < 2; ++c) {
      const int jp = bq * 2 + c;
      const float4 wa = wreg[2 * c], wb = wreg[2 * c + 1];
      short8v s0, s1;
      s0[0] = f2bf(wa.x); s0[1] = f2bf(wa.y);  s0[2] = f2bf(wa.z);  s0[3] = 0;
      s0[4] = f2bf(wb.x); s0[5] = f2bf(wb.y);  s0[6] = f2bf(wb.z);  s0[7] = 0;
      s1[0] = 0;          s1[1] = f2bf(wa.z);  s1[2] = f2bf(-wa.y); s1[3] = f2bf(wa.x);
      s1[4] = 0;          s1[5] = f2bf(wb.z);  s1[6] = f2bf(-wb.y); s1[7] = f2bf(wb.x);
      *(short8v*)&B_lds[bi * LDS_STRIDE + jp * 8]         = s0;
      *(short8v*)&B_lds[(256 + bi) * LDS_STRIDE + jp * 8] = s1;
    }
    if (t < 256) {
      short4v a;
      a[0] = f2bf(xreg.x); a[1] = f2bf(xreg.y); a[2] = f2bf(xreg.z); a[3] = f2bf(xs);
      *(short4v*)&A_lds[arow * LDS_STRIDE + aj * 4] = a;
    }
    // ---- prefetch next K-tile (flies during MFMA phase) ----
    if (it + 1 < 32) {
      const int jb = (it + 1) * 8;
#pragma unroll
      for (int c = 0; c < 2; ++c) {
        const int j0 = (bq * 2 + c) * 2;
        wreg[2 * c]     = W4[((jb + j0    ) * 256 + bi) * 2];
        wreg[2 * c + 1] = W4[((jb + j0 + 1) * 256 + bi) * 2];
      }
      if (t < 256) {
        const float* xp = xrowp + (jb + aj) * 8;
        xreg = *(const float4*)xp;
        xs   = xp[4];
      }
    }
    __syncthreads();
    // ---- compute: wave w owns cols [w*64, w*64+64) ----
    const bf16x8 a0 = *(const bf16x8*)&A_lds[ln * LDS_STRIDE + quad * 8];
    const bf16x8 a1 = *(const bf16x8*)&A_lds[(16 + ln) * LDS_STRIDE + quad * 8];
#pragma unroll
    for (int n = 0; n < 4; ++n) {
      const bf16x8 b =
          *(const bf16x8*)&B_lds[(w * 64 + n * 16 + ln) * LDS_STRIDE + quad * 8];
      acc[0][n] = __builtin_amdgcn_mfma_f32_16x16x32_bf16(a0, b, acc[0][n], 0, 0, 0);
      acc[1][n] = __builtin_amdgcn_mfma_f32_16x16x32_bf16(a1, b, acc[1][n], 0, 0, 0);
    }
    __syncthreads();
  }

  // ---- epilogue: two passes (c0 then c4) through LDS, coalesced float4 y writes ----
  const float4* bias4 = (const float4*)bias;
  float4* y4 = (float4*)y;
  const int ei  = t & 255;
  const int er2 = t >> 8;

#pragma unroll
  for (int h = 0; h < 2; ++h) {
    if ((w >> 2) == h) {  // waves [4h, 4h+4) hold cols [256h, 256h+256)
      const int colb = (w & 3) * 64;
#pragma unroll
      for (int m = 0; m < 2; ++m)
#pragma unroll
        for (int n = 0; n < 4; ++n)
#pragma unroll
          for (int r = 0; r < 4; ++r)
            c_lds[(m * 16 + quad * 4 + r) * C_STRIDE + colb + n * 16 + ln] =
                acc[m][n][r];
    }
    __syncthreads();
    const float4 bv = bias4[ei * 2 + h];
#pragma unroll
    for (int r0 = 0; r0 < 16; ++r0) {
      const int r = r0 * 2 + er2;
      float4 o = bv;
      o.x += c_lds[r * C_STRIDE + ei];   // y[..., 0] += c0  /  y[..., 4] += c4
      y4[((bm * 32 + r) * 256 + ei) * 2 + h] = o;
    }
    if (h == 0) __syncthreads();
  }
}

extern "C" void kernel_launch(void* const* d_in, const int* in_sizes, int n_in,
                              void* d_out, int out_size, void* d_ws, size_t ws_size,
                              hipStream_t stream) {
  const float* x    = (const float*)d_in[0];
  const float* W    = (const float*)d_in[1];
  const float* bias = (const float*)d_in[2];
  float* y = (float*)d_out;
  ga_mv_kernel<<<dim3(256), dim3(512), 0, stream>>>(x, W, bias, y);
}

// Round 2
// 163.431 us; speedup vs baseline: 1.0506x; 1.0506x over previous
//
#include <hip/hip_runtime.h>
#include <hip/hip_bf16.h>

typedef __attribute__((ext_vector_type(4))) float f32x4;
typedef __attribute__((ext_vector_type(8))) short bf16x8;
typedef __attribute__((ext_vector_type(4))) short short4v;
typedef __attribute__((ext_vector_type(8))) short short8v;

#define BSTRIDE 40    // shorts per B/A LDS row: 32 k + 8 pad = 80 B (16B-aligned; 20-bank stride -> 2-way=free)
#define CSTRIDE 532   // fp32 epilogue stride: quad offset 4*532=2128 dwords = 16 mod 32 -> 2-way (free)

__device__ __forceinline__ short f2bf(float f) {
  __hip_bfloat16 h = __float2bfloat16(f);
  return __builtin_bit_cast(short, h);
}

#define GLOAD_LDS16(gp, lp)                                                     \
  __builtin_amdgcn_global_load_lds(                                             \
      (const __attribute__((address_space(1))) void*)(gp),                      \
      (__attribute__((address_space(3))) void*)(lp), 16, 0, 0)

// ---------------------------------------------------------------------------
// GEMM view: C[8192 x 512] = A[8192 x 1024] * B[1024 x 512]
//   k = j*4 + kc, kc -> x component {0,1,2,4}
//   col <  256 (c0, i=col)    : B-row {W0, W1, W2, 0}
//   col >= 256 (c4, i=col-256): B-row {0, W2, -W1, W0}
// prep_B builds B_pre[it=0..31][col=0..511][BSTRIDE shorts] in d_ws, a
// byte-exact image of the main kernel's B LDS tile (pads included) so
// global_load_lds can copy it verbatim in 16B/lane chunks.
// ---------------------------------------------------------------------------
__global__ __launch_bounds__(256) void ga_prep_B(const float* __restrict__ W,
                                                 short* __restrict__ Bp) {
  const int gid = blockIdx.x * 256 + threadIdx.x;  // 16384 = 32 it * 512 col
  const int it = gid >> 9;
  const int col = gid & 511;
  const int hi = col >> 8;            // wave-uniform (blocks split at 256)
  const int i = col & 255;
  const float4* W4 = (const float4*)W;

  short8v out[5];
  out[4] = short8v{0, 0, 0, 0, 0, 0, 0, 0};  // pad shorts 32..39
#pragma unroll
  for (int jp = 0; jp < 8; ++jp) {
    const int j = it * 8 + jp;
    const float4 wv = W4[(j * 256 + i) * 2];  // comps 0..3 of W[j][i][:]
    short s0, s1, s2, s3;
    if (!hi) { s0 = f2bf(wv.x); s1 = f2bf(wv.y); s2 = f2bf(wv.z); s3 = 0; }
    else     { s0 = 0; s1 = f2bf(wv.z); s2 = f2bf(-wv.y); s3 = f2bf(wv.x); }
    out[jp >> 1][(jp & 1) * 4 + 0] = s0;
    out[jp >> 1][(jp & 1) * 4 + 1] = s1;
    out[jp >> 1][(jp & 1) * 4 + 2] = s2;
    out[jp >> 1][(jp & 1) * 4 + 3] = s3;
  }
  short8v* dst = (short8v*)&Bp[(size_t)gid * BSTRIDE];
#pragma unroll
  for (int c = 0; c < 5; ++c) dst[c] = out[c];
}

// ---------------------------------------------------------------------------
// Main: 512 blocks (16 rows x 512 cols each), 256 threads (4 waves) ->
// 2 blocks/CU so barrier drains of one block overlap the other's work.
// x read exactly once from HBM. B staged per K-step from L2 via
// global_load_lds width=16. Epilogue: full-multivector contiguous writes.
// ---------------------------------------------------------------------------
__global__ __launch_bounds__(256, 2) void ga_mv_main(
    const float* __restrict__ x, const short* __restrict__ Bp,
    const float* __restrict__ bias, float* __restrict__ y) {
  __shared__ __align__(16) short B_lds[512 * BSTRIDE];  // 40960 B
  __shared__ __align__(16) short A_lds[16 * BSTRIDE];   // 1280 B
  float* c_lds = (float*)&B_lds[0];  // epilogue alias: 16*532*4 = 34048 <= 40960

  const int t = threadIdx.x;
  const int bm = blockIdx.x;        // 512 blocks x 16 rows
  const int lane = t & 63;
  const int w = t >> 6;             // 4 waves; wave w owns cols [w*128, w*128+128)
  const int ln = lane & 15;
  const int quad = lane >> 4;

  // A staging: threads 0..127 -> (row = t>>3, j = t&7)
  const int ar = (t >> 3) & 15;
  const int aj = t & 7;
  const float* xrowp = x + (size_t)(bm * 16 + ar) * 2048;

  float4 xreg;
  float xs = 0.f;
  if (t < 128) {
    const float* xp = xrowp + aj * 8;
    xreg = *(const float4*)xp;
    xs = xp[4];
  }

  f32x4 acc[8] = {};

  for (int it = 0; it < 32; ++it) {
    // ---- async stage B-tile (byte-image) global -> LDS: 10 x 4KB rounds ----
    const char* bsrc = (const char*)Bp + (size_t)it * 40960;
    char* bdst = (char*)&B_lds[0];
#pragma unroll
    for (int r = 0; r < 10; ++r)
      GLOAD_LDS16(bsrc + r * 4096 + t * 16, bdst + r * 4096 + t * 16);

    // ---- A: convert prefetched x regs -> LDS ----
    if (t < 128) {
      short4v a;
      a[0] = f2bf(xreg.x); a[1] = f2bf(xreg.y); a[2] = f2bf(xreg.z); a[3] = f2bf(xs);
      *(short4v*)&A_lds[ar * BSTRIDE + aj * 4] = a;
    }
    // ---- prefetch next x K-slice ----
    if (it + 1 < 32 && t < 128) {
      const float* xp = xrowp + ((it + 1) * 8 + aj) * 8;
      xreg = *(const float4*)xp;
      xs = xp[4];
    }
    __syncthreads();  // drains global_load_lds (vmcnt) + ds writes (lgkm)

    // ---- compute: 1 A-frag, 8 B-frags, 8 MFMA ----
    const bf16x8 a0 = *(const bf16x8*)&A_lds[ln * BSTRIDE + quad * 8];
#pragma unroll
    for (int nb = 0; nb < 8; ++nb) {
      const bf16x8 b =
          *(const bf16x8*)&B_lds[(w * 128 + nb * 16 + ln) * BSTRIDE + quad * 8];
      acc[nb] = __builtin_amdgcn_mfma_f32_16x16x32_bf16(a0, b, acc[nb], 0, 0, 0);
    }
    __syncthreads();  // protect B_lds/A_lds overwrite next iter
  }

  // ---- epilogue: acc -> c_lds, then contiguous full-line y writes ----
  // C/D layout (16x16): col = ln, row = quad*4 + reg
#pragma unroll
  for (int nb = 0; nb < 8; ++nb)
#pragma unroll
    for (int r = 0; r < 4; ++r)
      c_lds[(quad * 4 + r) * CSTRIDE + w * 128 + nb * 16 + ln] = acc[nb][r];
  __syncthreads();

  const float4* bias4 = (const float4*)bias;
  float4* y4 = (float4*)y;
  const int half = t & 1;   // 0 -> mv comps 0..3 (c0), 1 -> comps 4..7 (c4)
  const int pp = t >> 1;    // point within 128-point pass
#pragma unroll
  for (int pass = 0; pass < 2; ++pass) {
    const int p = pass * 128 + pp;  // output column i
    float4 bv = bias4[p * 2 + half];
#pragma unroll
    for (int r = 0; r < 16; ++r) {
      float4 o = bv;
      o.x += c_lds[r * CSTRIDE + half * 256 + p];  // +c0 into comp0 / +c4 into comp4
      y4[((size_t)(bm * 16 + r) * 256 + p) * 2 + half] = o;  // lane-consecutive 16B
    }
  }
}

extern "C" void kernel_launch(void* const* d_in, const int* in_sizes, int n_in,
                              void* d_out, int out_size, void* d_ws, size_t ws_size,
                              hipStream_t stream) {
  const float* x = (const float*)d_in[0];
  const float* W = (const float*)d_in[1];
  const float* bias = (const float*)d_in[2];
  float* y = (float*)d_out;
  short* Bp = (short*)d_ws;  // 32*512*40*2 = 1,310,720 B

  ga_prep_B<<<dim3(64), dim3(256), 0, stream>>>(W, Bp);
  ga_mv_main<<<dim3(512), dim3(256), 0, stream>>>(x, Bp, bias, y);
}